// Round 1
// baseline (500.868 us; speedup 1.0000x reference)
//
#include <hip/hip_runtime.h>
#include <cstdint>

#define N_NODES 50000
#define N_EDGES 800000
#define D 128

// ---------------------------------------------------------------------------
// QKV GEMM: O = emb @ W for W in {Wq,Wk,Wv}  (M=50000, N=K=128, fp32)
// blockIdx.y selects which of the three. Weight (64KB) + 32-row A tile in LDS.
// Thread microtile: 2 rows x 8 cols (16 acc regs).
// ---------------------------------------------------------------------------
__global__ __launch_bounds__(256) void qkv_gemm(
    const float* __restrict__ emb,
    const float* __restrict__ Wq, const float* __restrict__ Wk,
    const float* __restrict__ Wv,
    float* __restrict__ Q, float* __restrict__ K, float* __restrict__ V)
{
    __shared__ float sW[D * D];      // 64 KB
    __shared__ float sA[32 * D];     // 16 KB  (80 KB total -> 2 blocks/CU)

    const float* W = (blockIdx.y == 0) ? Wq : (blockIdx.y == 1) ? Wk : Wv;
    float*       O = (blockIdx.y == 0) ? Q  : (blockIdx.y == 1) ? K  : V;

    const int t  = threadIdx.x;
    for (int i = t; i < D * D; i += 256) sW[i] = W[i];

    const int cg = t & 15;        // col group: cols cg*8 .. cg*8+7
    const int rp = t >> 4;        // row pair:  rows 2*rp, 2*rp+1
    const int r0 = rp * 2, r1 = r0 + 1;

    for (int base = blockIdx.x * 32; base < N_NODES; base += gridDim.x * 32) {
        __syncthreads();  // protect sA from previous iteration / sW first time
        const int rows = min(32, N_NODES - base);
        for (int i = t; i < rows * D; i += 256) sA[i] = emb[base * D + i];
        __syncthreads();

        float4 a00 = {0,0,0,0}, a01 = {0,0,0,0};
        float4 a10 = {0,0,0,0}, a11 = {0,0,0,0};
        #pragma unroll 4
        for (int k = 0; k < D; ++k) {
            const float v0 = sA[r0 * D + k];
            const float v1 = sA[r1 * D + k];
            const float4* wb = (const float4*)(sW + k * D + cg * 8);
            const float4 b0 = wb[0];
            const float4 b1 = wb[1];
            a00.x += v0 * b0.x; a00.y += v0 * b0.y; a00.z += v0 * b0.z; a00.w += v0 * b0.w;
            a01.x += v0 * b1.x; a01.y += v0 * b1.y; a01.z += v0 * b1.z; a01.w += v0 * b1.w;
            a10.x += v1 * b0.x; a10.y += v1 * b0.y; a10.z += v1 * b0.z; a10.w += v1 * b0.w;
            a11.x += v1 * b1.x; a11.y += v1 * b1.y; a11.z += v1 * b1.z; a11.w += v1 * b1.w;
        }
        if (base + r0 < N_NODES) {
            float4* o = (float4*)(O + (size_t)(base + r0) * D + cg * 8);
            o[0] = a00; o[1] = a01;
        }
        if (base + r1 < N_NODES) {
            float4* o = (float4*)(O + (size_t)(base + r1) * D + cg * 8);
            o[0] = a10; o[1] = a11;
        }
    }
}

// ---------------------------------------------------------------------------
// CSR build: counts -> exclusive scan (offsets, cursor) -> fill col indices
// ---------------------------------------------------------------------------
__global__ void count_edges(const int* __restrict__ rows, int* __restrict__ counts)
{
    int e = blockIdx.x * blockDim.x + threadIdx.x;
    if (e < N_EDGES) atomicAdd(&counts[rows[e]], 1);
}

__global__ __launch_bounds__(1024) void scan_offsets(
    const int* __restrict__ counts, int* __restrict__ offsets, int* __restrict__ cursor)
{
    __shared__ int sd[1024];
    __shared__ int s_run;
    const int t = threadIdx.x;
    if (t == 0) s_run = 0;
    __syncthreads();
    for (int base = 0; base < N_NODES; base += 1024) {
        const int idx = base + t;
        const int x = (idx < N_NODES) ? counts[idx] : 0;
        int val = x;
        sd[t] = val;
        __syncthreads();
        for (int off = 1; off < 1024; off <<= 1) {
            const int y = (t >= off) ? sd[t - off] : 0;
            __syncthreads();
            val += y;
            sd[t] = val;
            __syncthreads();
        }
        const int run = s_run;
        if (idx < N_NODES) {
            const int excl = run + val - x;
            offsets[idx] = excl;
            cursor[idx]  = excl;
        }
        __syncthreads();
        if (t == 1023) s_run = run + sd[1023];
        __syncthreads();
    }
    if (t == 0) offsets[N_NODES] = s_run;
}

__global__ void fill_csr(const int* __restrict__ rows, const int* __restrict__ cols,
                         int* __restrict__ cursor, int* __restrict__ colIdx)
{
    int e = blockIdx.x * blockDim.x + threadIdx.x;
    if (e < N_EDGES) {
        const int pos = atomicAdd(&cursor[rows[e]], 1);
        colIdx[pos] = cols[e];
    }
}

// ---------------------------------------------------------------------------
// Node attention: one 64-lane wave per destination node.
// lane l owns dims {2l, 2l+1}; head h = lanes 8h..8h+7 (16 dims).
// Single pass: accumulate sum(w*v) and sum(w), divide, +residual, LayerNorm.
// ---------------------------------------------------------------------------
__global__ __launch_bounds__(256) void node_attn(
    const float* __restrict__ Q, const float* __restrict__ K,
    const float* __restrict__ V, const float* __restrict__ emb,
    const int* __restrict__ offsets, const int* __restrict__ colIdx,
    const float* __restrict__ gam, const float* __restrict__ bet,
    float* __restrict__ out)
{
    const int node = (int)((blockIdx.x * blockDim.x + threadIdx.x) >> 6);
    if (node >= N_NODES) return;
    const int lane = threadIdx.x & 63;
    const int d0 = lane * 2;

    const float2 q = *(const float2*)(Q   + (size_t)node * D + d0);
    const float2 r = *(const float2*)(emb + (size_t)node * D + d0);

    const int s = offsets[node];
    const int e = offsets[node + 1];

    float nx = 0.f, ny = 0.f, den = 0.f;
    int i = s;
    for (; i + 2 <= e; i += 2) {
        const int c0 = colIdx[i];
        const int c1 = colIdx[i + 1];
        const float2 k0 = *(const float2*)(K + (size_t)c0 * D + d0);
        const float2 v0 = *(const float2*)(V + (size_t)c0 * D + d0);
        const float2 k1 = *(const float2*)(K + (size_t)c1 * D + d0);
        const float2 v1 = *(const float2*)(V + (size_t)c1 * D + d0);
        float p0 = q.x * k0.x + q.y * k0.y;
        float p1 = q.x * k1.x + q.y * k1.y;
        p0 += __shfl_xor(p0, 1); p0 += __shfl_xor(p0, 2); p0 += __shfl_xor(p0, 4);
        p1 += __shfl_xor(p1, 1); p1 += __shfl_xor(p1, 2); p1 += __shfl_xor(p1, 4);
        const float w0 = __expf(fminf(10.f, fmaxf(-10.f, p0)));
        const float w1 = __expf(fminf(10.f, fmaxf(-10.f, p1)));
        den += w0 + w1;
        nx += w0 * v0.x + w1 * v1.x;
        ny += w0 * v0.y + w1 * v1.y;
    }
    if (i < e) {
        const int c0 = colIdx[i];
        const float2 k0 = *(const float2*)(K + (size_t)c0 * D + d0);
        const float2 v0 = *(const float2*)(V + (size_t)c0 * D + d0);
        float p0 = q.x * k0.x + q.y * k0.y;
        p0 += __shfl_xor(p0, 1); p0 += __shfl_xor(p0, 2); p0 += __shfl_xor(p0, 4);
        const float w0 = __expf(fminf(10.f, fmaxf(-10.f, p0)));
        den += w0;
        nx += w0 * v0.x;
        ny += w0 * v0.y;
    }

    const float inv = 1.f / (den + 1e-8f);
    const float rx = nx * inv + r.x;
    const float ry = ny * inv + r.y;

    // LayerNorm over the wave's 128 values
    float sum = rx + ry;
    float ssq = rx * rx + ry * ry;
    #pragma unroll
    for (int o = 1; o < 64; o <<= 1) {
        sum += __shfl_xor(sum, o);
        ssq += __shfl_xor(ssq, o);
    }
    const float mu   = sum * (1.f / 128.f);
    const float var  = ssq * (1.f / 128.f) - mu * mu;
    const float rstd = rsqrtf(var + 1e-6f);

    const float2 g = *(const float2*)(gam + d0);
    const float2 b = *(const float2*)(bet + d0);
    float2 o2;
    o2.x = (rx - mu) * rstd * g.x + b.x;
    o2.y = (ry - mu) * rstd * g.y + b.y;
    *(float2*)(out + (size_t)node * D + d0) = o2;
}

// ---------------------------------------------------------------------------
extern "C" void kernel_launch(void* const* d_in, const int* in_sizes, int n_in,
                              void* d_out, int out_size, void* d_ws, size_t ws_size,
                              hipStream_t stream)
{
    const float* emb  = (const float*)d_in[0];
    const int*   ei   = (const int*)d_in[1];     // [2, N_EDGES] int
    const float* Wq   = (const float*)d_in[2];
    const float* Wk   = (const float*)d_in[3];
    const float* Wv   = (const float*)d_in[4];
    const float* gam  = (const float*)d_in[5];
    const float* bet  = (const float*)d_in[6];
    float*       out  = (float*)d_out;

    const int* rows = ei;
    const int* cols = ei + N_EDGES;

    // workspace layout (256B aligned chunks)
    char* ws = (char*)d_ws;
    auto alloc = [&](size_t bytes) {
        char* p = ws;
        ws += (bytes + 255) & ~size_t(255);
        return p;
    };
    float* Q       = (float*)alloc((size_t)N_NODES * D * sizeof(float));
    float* K       = (float*)alloc((size_t)N_NODES * D * sizeof(float));
    float* V       = (float*)alloc((size_t)N_NODES * D * sizeof(float));
    int*   counts  = (int*)alloc((size_t)N_NODES * sizeof(int));
    int*   offsets = (int*)alloc((size_t)(N_NODES + 1) * sizeof(int));
    int*   cursor  = (int*)alloc((size_t)N_NODES * sizeof(int));
    int*   colIdx  = (int*)alloc((size_t)N_EDGES * sizeof(int));

    hipMemsetAsync(counts, 0, (size_t)N_NODES * sizeof(int), stream);

    qkv_gemm<<<dim3(200, 3), 256, 0, stream>>>(emb, Wq, Wk, Wv, Q, K, V);

    const int eb = (N_EDGES + 255) / 256;
    count_edges<<<eb, 256, 0, stream>>>(rows, counts);
    scan_offsets<<<1, 1024, 0, stream>>>(counts, offsets, cursor);
    fill_csr<<<eb, 256, 0, stream>>>(rows, cols, cursor, colIdx);

    node_attn<<<(N_NODES * 64 + 255) / 256, 256, 0, stream>>>(
        Q, K, V, emb, offsets, colIdx, gam, bet, out);
}

// Round 2
// 427.444 us; speedup vs baseline: 1.1718x; 1.1718x over previous
//
#include <hip/hip_runtime.h>
#include <cstdint>

#define N_NODES 50000
#define N_EDGES 800000
#define D 128

typedef __attribute__((ext_vector_type(8))) short short8;
typedef __attribute__((ext_vector_type(4))) float float4v;
typedef unsigned short ushort_t;
typedef unsigned int uint_t;

__device__ __forceinline__ ushort_t f2bf(float f) {
    uint_t u = __float_as_uint(f);
    u += 0x7FFFu + ((u >> 16) & 1u);   // round-to-nearest-even
    return (ushort_t)(u >> 16);
}

// ---------------------------------------------------------------------------
// Convert emb (fp32) -> bf16 row-major. 8 floats per thread.
// ---------------------------------------------------------------------------
__global__ __launch_bounds__(256) void conv_emb(const float* __restrict__ emb,
                                                ushort_t* __restrict__ embB)
{
    const int i = (blockIdx.x * blockDim.x + threadIdx.x) * 8;
    if (i >= N_NODES * D) return;
    const float4 f0 = *(const float4*)(emb + i);
    const float4 f1 = *(const float4*)(emb + i + 4);
    ushort_t r[8];
    r[0]=f2bf(f0.x); r[1]=f2bf(f0.y); r[2]=f2bf(f0.z); r[3]=f2bf(f0.w);
    r[4]=f2bf(f1.x); r[5]=f2bf(f1.y); r[6]=f2bf(f1.z); r[7]=f2bf(f1.w);
    *(int4*)(embB + i) = *(int4*)r;
}

// ---------------------------------------------------------------------------
// Repack W [K=128][N=128] row-major fp32 -> bf16 in MFMA B-fragment order:
// frag index f = kk*8 + nt (kk: K-chunk of 32, nt: N-tile of 16)
// Wp[(f*64 + lane)*8 + j] = W[kk*32 + (lane>>4)*8 + j][nt*16 + (lane&15)]
// blockIdx.x selects which of the 3 weight matrices.
// ---------------------------------------------------------------------------
__global__ __launch_bounds__(256) void repack_w(
    const float* __restrict__ Wq, const float* __restrict__ Wk,
    const float* __restrict__ Wv, ushort_t* __restrict__ WpAll)
{
    const float* W = (blockIdx.x == 0) ? Wq : (blockIdx.x == 1) ? Wk : Wv;
    ushort_t* Wp = WpAll + blockIdx.x * (D * D);
    for (int i = threadIdx.x; i < D * D; i += 256) {
        const int j    = i & 7;
        const int lane = (i >> 3) & 63;
        const int f    = i >> 9;
        const int kk = f >> 3, nt = f & 7;
        const int k = kk * 32 + (lane >> 4) * 8 + j;
        const int n = nt * 16 + (lane & 15);
        Wp[i] = f2bf(W[k * D + n]);
    }
}

// ---------------------------------------------------------------------------
// QKV GEMM via MFMA 16x16x32 bf16 (fp32 accumulate).
// Block = 256 thr (4 waves) = 64 rows; wave = 16-row strip x 128 cols.
// W (packed) staged in LDS (32 KB); A-frags loaded straight from embB.
// ---------------------------------------------------------------------------
__global__ __launch_bounds__(256) void qkv_mfma(
    const ushort_t* __restrict__ embB, const ushort_t* __restrict__ WpAll,
    float* __restrict__ Q, float* __restrict__ K, float* __restrict__ V)
{
    __shared__ ushort_t sB[D * D];   // 32 KB

    const ushort_t* Wp = WpAll + blockIdx.y * (D * D);
    float* O = (blockIdx.y == 0) ? Q : (blockIdx.y == 1) ? K : V;

    const int t = threadIdx.x;
    for (int i = t * 8; i < D * D; i += 256 * 8)
        *(int4*)(sB + i) = *(const int4*)(Wp + i);
    __syncthreads();

    const int wave = t >> 6;
    const int lane = t & 63;
    const int row0 = blockIdx.x * 64 + wave * 16;
    const int m    = lane & 15;
    const int q    = lane >> 4;

    // A fragments: row (row0+m), k = kk*32 + q*8 + j  (8 contiguous bf16)
    const int arow = min(row0 + m, N_NODES - 1);
    const ushort_t* abase = embB + (size_t)arow * D + q * 8;
    short8 a[4];
    #pragma unroll
    for (int kk = 0; kk < 4; ++kk)
        a[kk] = *(const short8*)(abase + kk * 32);

    float4v acc[8];
    #pragma unroll
    for (int nt = 0; nt < 8; ++nt) acc[nt] = (float4v){0.f, 0.f, 0.f, 0.f};

    #pragma unroll
    for (int kk = 0; kk < 4; ++kk) {
        #pragma unroll
        for (int nt = 0; nt < 8; ++nt) {
            const short8 b = *(const short8*)(sB + ((kk * 8 + nt) * 64 + lane) * 8);
            acc[nt] = __builtin_amdgcn_mfma_f32_16x16x32_bf16(a[kk], b, acc[nt], 0, 0, 0);
        }
    }

    // C/D: col = lane&15, row = q*4 + reg
    #pragma unroll
    for (int nt = 0; nt < 8; ++nt) {
        #pragma unroll
        for (int r = 0; r < 4; ++r) {
            const int row = row0 + q * 4 + r;
            if (row < N_NODES)
                O[(size_t)row * D + nt * 16 + m] = acc[nt][r];
        }
    }
}

// ---------------------------------------------------------------------------
// CSR build
// ---------------------------------------------------------------------------
__global__ void count_edges(const int* __restrict__ rows, int* __restrict__ counts)
{
    int e = blockIdx.x * blockDim.x + threadIdx.x;
    if (e < N_EDGES) atomicAdd(&counts[rows[e]], 1);
}

// Thread-coarsened single-block scan: 1024 threads x 49-elem serial chunks.
__global__ __launch_bounds__(1024) void scan_offsets(
    const int* __restrict__ counts, int* __restrict__ offsets, int* __restrict__ cursor)
{
    __shared__ int sd[1024];
    const int t = threadIdx.x;
    const int per = (N_NODES + 1023) / 1024;   // 49
    const int start = t * per;
    const int end   = min(start + per, N_NODES);

    int s = 0;
    for (int i = start; i < end; ++i) s += counts[i];

    sd[t] = s;
    __syncthreads();
    int val = s;
    #pragma unroll
    for (int off = 1; off < 1024; off <<= 1) {
        const int y = (t >= off) ? sd[t - off] : 0;
        __syncthreads();
        val += y;
        sd[t] = val;
        __syncthreads();
    }

    int run = val - s;   // exclusive prefix of this chunk
    for (int i = start; i < end; ++i) {
        offsets[i] = run;
        cursor[i]  = run;
        run += counts[i];
    }
    if (t == 1023) offsets[N_NODES] = run;
}

__global__ void fill_csr(const int* __restrict__ rows, const int* __restrict__ cols,
                         int* __restrict__ cursor, int* __restrict__ colIdx)
{
    int e = blockIdx.x * blockDim.x + threadIdx.x;
    if (e < N_EDGES) {
        const int pos = atomicAdd(&cursor[rows[e]], 1);
        colIdx[pos] = cols[e];
    }
}

// ---------------------------------------------------------------------------
// Node attention: one 64-lane wave per destination node.
// ---------------------------------------------------------------------------
__global__ __launch_bounds__(256) void node_attn(
    const float* __restrict__ Q, const float* __restrict__ K,
    const float* __restrict__ V, const float* __restrict__ emb,
    const int* __restrict__ offsets, const int* __restrict__ colIdx,
    const float* __restrict__ gam, const float* __restrict__ bet,
    float* __restrict__ out)
{
    const int node = (int)((blockIdx.x * blockDim.x + threadIdx.x) >> 6);
    if (node >= N_NODES) return;
    const int lane = threadIdx.x & 63;
    const int d0 = lane * 2;

    const float2 q = *(const float2*)(Q   + (size_t)node * D + d0);
    const float2 r = *(const float2*)(emb + (size_t)node * D + d0);

    const int s = offsets[node];
    const int e = offsets[node + 1];

    float nx = 0.f, ny = 0.f, den = 0.f;
    int i = s;
    for (; i + 2 <= e; i += 2) {
        const int c0 = colIdx[i];
        const int c1 = colIdx[i + 1];
        const float2 k0 = *(const float2*)(K + (size_t)c0 * D + d0);
        const float2 v0 = *(const float2*)(V + (size_t)c0 * D + d0);
        const float2 k1 = *(const float2*)(K + (size_t)c1 * D + d0);
        const float2 v1 = *(const float2*)(V + (size_t)c1 * D + d0);
        float p0 = q.x * k0.x + q.y * k0.y;
        float p1 = q.x * k1.x + q.y * k1.y;
        p0 += __shfl_xor(p0, 1); p0 += __shfl_xor(p0, 2); p0 += __shfl_xor(p0, 4);
        p1 += __shfl_xor(p1, 1); p1 += __shfl_xor(p1, 2); p1 += __shfl_xor(p1, 4);
        const float w0 = __expf(fminf(10.f, fmaxf(-10.f, p0)));
        const float w1 = __expf(fminf(10.f, fmaxf(-10.f, p1)));
        den += w0 + w1;
        nx += w0 * v0.x + w1 * v1.x;
        ny += w0 * v0.y + w1 * v1.y;
    }
    if (i < e) {
        const int c0 = colIdx[i];
        const float2 k0 = *(const float2*)(K + (size_t)c0 * D + d0);
        const float2 v0 = *(const float2*)(V + (size_t)c0 * D + d0);
        float p0 = q.x * k0.x + q.y * k0.y;
        p0 += __shfl_xor(p0, 1); p0 += __shfl_xor(p0, 2); p0 += __shfl_xor(p0, 4);
        const float w0 = __expf(fminf(10.f, fmaxf(-10.f, p0)));
        den += w0;
        nx += w0 * v0.x;
        ny += w0 * v0.y;
    }

    const float inv = 1.f / (den + 1e-8f);
    const float rx = nx * inv + r.x;
    const float ry = ny * inv + r.y;

    float sum = rx + ry;
    float ssq = rx * rx + ry * ry;
    #pragma unroll
    for (int o = 1; o < 64; o <<= 1) {
        sum += __shfl_xor(sum, o);
        ssq += __shfl_xor(ssq, o);
    }
    const float mu   = sum * (1.f / 128.f);
    const float var  = ssq * (1.f / 128.f) - mu * mu;
    const float rstd = rsqrtf(var + 1e-6f);

    const float2 g = *(const float2*)(gam + d0);
    const float2 b = *(const float2*)(bet + d0);
    float2 o2;
    o2.x = (rx - mu) * rstd * g.x + b.x;
    o2.y = (ry - mu) * rstd * g.y + b.y;
    *(float2*)(out + (size_t)node * D + d0) = o2;
}

// ---------------------------------------------------------------------------
extern "C" void kernel_launch(void* const* d_in, const int* in_sizes, int n_in,
                              void* d_out, int out_size, void* d_ws, size_t ws_size,
                              hipStream_t stream)
{
    const float* emb  = (const float*)d_in[0];
    const int*   ei   = (const int*)d_in[1];
    const float* Wq   = (const float*)d_in[2];
    const float* Wk   = (const float*)d_in[3];
    const float* Wv   = (const float*)d_in[4];
    const float* gam  = (const float*)d_in[5];
    const float* bet  = (const float*)d_in[6];
    float*       out  = (float*)d_out;

    const int* rows = ei;
    const int* cols = ei + N_EDGES;

    char* ws = (char*)d_ws;
    auto alloc = [&](size_t bytes) {
        char* p = ws;
        ws += (bytes + 255) & ~size_t(255);
        return p;
    };
    float*    Q       = (float*)alloc((size_t)N_NODES * D * sizeof(float));
    float*    K       = (float*)alloc((size_t)N_NODES * D * sizeof(float));
    float*    V       = (float*)alloc((size_t)N_NODES * D * sizeof(float));
    ushort_t* embB    = (ushort_t*)alloc((size_t)N_NODES * D * sizeof(ushort_t));
    ushort_t* WpAll   = (ushort_t*)alloc((size_t)3 * D * D * sizeof(ushort_t));
    int*      counts  = (int*)alloc((size_t)N_NODES * sizeof(int));
    int*      offsets = (int*)alloc((size_t)(N_NODES + 1) * sizeof(int));
    int*      cursor  = (int*)alloc((size_t)N_NODES * sizeof(int));
    int*      colIdx  = (int*)alloc((size_t)N_EDGES * sizeof(int));

    hipMemsetAsync(counts, 0, (size_t)N_NODES * sizeof(int), stream);

    conv_emb<<<(N_NODES * D / 8 + 255) / 256, 256, 0, stream>>>(emb, embB);
    repack_w<<<3, 256, 0, stream>>>(Wq, Wk, Wv, WpAll);
    qkv_mfma<<<dim3((N_NODES + 63) / 64, 3), 256, 0, stream>>>(embB, WpAll, Q, K, V);

    const int eb = (N_EDGES + 255) / 256;
    count_edges<<<eb, 256, 0, stream>>>(rows, counts);
    scan_offsets<<<1, 1024, 0, stream>>>(counts, offsets, cursor);
    fill_csr<<<eb, 256, 0, stream>>>(rows, cols, cursor, colIdx);

    node_attn<<<(N_NODES * 64 + 255) / 256, 256, 0, stream>>>(
        Q, K, V, emb, offsets, colIdx, gam, bet, out);
}

// Round 3
// 366.891 us; speedup vs baseline: 1.3652x; 1.1650x over previous
//
#include <hip/hip_runtime.h>
#include <hip/hip_fp16.h>
#include <cstdint>

#define N_NODES 50000
#define N_EDGES 800000
#define D 128

typedef _Float16 half8 __attribute__((ext_vector_type(8)));
typedef __attribute__((ext_vector_type(4))) float float4v;
typedef unsigned short ushort_t;

__device__ __forceinline__ ushort_t f2h(float f) {
    return __half_as_ushort(__float2half(f));   // RNE hardware cvt
}

// ---------------------------------------------------------------------------
// Convert emb (fp32) -> fp16 row-major. 8 floats per thread.
// ---------------------------------------------------------------------------
__global__ __launch_bounds__(256) void conv_emb(const float* __restrict__ emb,
                                                ushort_t* __restrict__ embH)
{
    const int i = (blockIdx.x * blockDim.x + threadIdx.x) * 8;
    if (i >= N_NODES * D) return;
    const float4 f0 = *(const float4*)(emb + i);
    const float4 f1 = *(const float4*)(emb + i + 4);
    ushort_t r[8];
    r[0]=f2h(f0.x); r[1]=f2h(f0.y); r[2]=f2h(f0.z); r[3]=f2h(f0.w);
    r[4]=f2h(f1.x); r[5]=f2h(f1.y); r[6]=f2h(f1.z); r[7]=f2h(f1.w);
    *(int4*)(embH + i) = *(int4*)r;
}

// ---------------------------------------------------------------------------
// Repack W [K=128][N=128] row-major fp32 -> fp16 in MFMA B-fragment order:
// Wp[((kk*8+nt)*64 + lane)*8 + j] = W[kk*32 + (lane>>4)*8 + j][nt*16 + (lane&15)]
// ---------------------------------------------------------------------------
__global__ __launch_bounds__(256) void repack_w(
    const float* __restrict__ Wq, const float* __restrict__ Wk,
    const float* __restrict__ Wv, ushort_t* __restrict__ WpAll)
{
    const float* W = (blockIdx.x == 0) ? Wq : (blockIdx.x == 1) ? Wk : Wv;
    ushort_t* Wp = WpAll + blockIdx.x * (D * D);
    for (int i = threadIdx.x; i < D * D; i += 256) {
        const int j    = i & 7;
        const int lane = (i >> 3) & 63;
        const int f    = i >> 9;
        const int kk = f >> 3, nt = f & 7;
        const int k = kk * 32 + (lane >> 4) * 8 + j;
        const int n = nt * 16 + (lane & 15);
        Wp[i] = f2h(W[k * D + n]);
    }
}

// ---------------------------------------------------------------------------
// QKV GEMM via MFMA 16x16x32 f16 (fp32 accumulate), outputs stored fp16.
// Block = 256 thr (4 waves) = 64 rows; wave = 16-row strip x 128 cols.
// ---------------------------------------------------------------------------
__global__ __launch_bounds__(256) void qkv_mfma(
    const ushort_t* __restrict__ embH, const ushort_t* __restrict__ WpAll,
    ushort_t* __restrict__ Qh, ushort_t* __restrict__ Kh, ushort_t* __restrict__ Vh)
{
    __shared__ ushort_t sB[D * D];   // 32 KB

    const ushort_t* Wp = WpAll + blockIdx.y * (D * D);
    ushort_t* O = (blockIdx.y == 0) ? Qh : (blockIdx.y == 1) ? Kh : Vh;

    const int t = threadIdx.x;
    for (int i = t * 8; i < D * D; i += 256 * 8)
        *(int4*)(sB + i) = *(const int4*)(Wp + i);
    __syncthreads();

    const int wave = t >> 6;
    const int lane = t & 63;
    const int row0 = blockIdx.x * 64 + wave * 16;
    const int m    = lane & 15;
    const int q    = lane >> 4;

    const int arow = min(row0 + m, N_NODES - 1);
    const ushort_t* abase = embH + (size_t)arow * D + q * 8;
    half8 a[4];
    #pragma unroll
    for (int kk = 0; kk < 4; ++kk)
        a[kk] = *(const half8*)(abase + kk * 32);

    float4v acc[8];
    #pragma unroll
    for (int nt = 0; nt < 8; ++nt) acc[nt] = (float4v){0.f, 0.f, 0.f, 0.f};

    #pragma unroll
    for (int kk = 0; kk < 4; ++kk) {
        #pragma unroll
        for (int nt = 0; nt < 8; ++nt) {
            const half8 b = *(const half8*)(sB + ((kk * 8 + nt) * 64 + lane) * 8);
            acc[nt] = __builtin_amdgcn_mfma_f32_16x16x32_f16(a[kk], b, acc[nt], 0, 0, 0);
        }
    }

    // C/D: col = lane&15, row = q*4 + reg
    #pragma unroll
    for (int nt = 0; nt < 8; ++nt) {
        #pragma unroll
        for (int r = 0; r < 4; ++r) {
            const int row = row0 + q * 4 + r;
            if (row < N_NODES)
                O[(size_t)row * D + nt * 16 + m] = f2h(acc[nt][r]);
        }
    }
}

// ---------------------------------------------------------------------------
// CSR build
// ---------------------------------------------------------------------------
__global__ void count_edges(const int* __restrict__ rows, int* __restrict__ counts)
{
    int e = blockIdx.x * blockDim.x + threadIdx.x;
    if (e < N_EDGES) atomicAdd(&counts[rows[e]], 1);
}

__global__ __launch_bounds__(1024) void scan_offsets(
    const int* __restrict__ counts, int* __restrict__ offsets, int* __restrict__ cursor)
{
    __shared__ int sd[1024];
    const int t = threadIdx.x;
    const int per = (N_NODES + 1023) / 1024;   // 49
    const int start = t * per;
    const int end   = min(start + per, N_NODES);

    int s = 0;
    for (int i = start; i < end; ++i) s += counts[i];

    sd[t] = s;
    __syncthreads();
    int val = s;
    #pragma unroll
    for (int off = 1; off < 1024; off <<= 1) {
        const int y = (t >= off) ? sd[t - off] : 0;
        __syncthreads();
        val += y;
        sd[t] = val;
        __syncthreads();
    }

    int run = val - s;
    for (int i = start; i < end; ++i) {
        offsets[i] = run;
        cursor[i]  = run;
        run += counts[i];
    }
    if (t == 1023) offsets[N_NODES] = run;
}

__global__ void fill_csr(const int* __restrict__ rows, const int* __restrict__ cols,
                         int* __restrict__ cursor, int* __restrict__ colIdx)
{
    int e = blockIdx.x * blockDim.x + threadIdx.x;
    if (e < N_EDGES) {
        const int pos = atomicAdd(&cursor[rows[e]], 1);
        colIdx[pos] = cols[e];
    }
}

// ---------------------------------------------------------------------------
// Node attention: one 64-lane wave per destination node; fp16 Q/K/V gather.
// lane l owns dims {2l, 2l+1}; head h = lanes 8h..8h+7.
// ---------------------------------------------------------------------------
__device__ __forceinline__ float hsum(float p) {
    p += __shfl_xor(p, 1); p += __shfl_xor(p, 2); p += __shfl_xor(p, 4);
    return p;
}

__global__ __launch_bounds__(256) void node_attn(
    const ushort_t* __restrict__ Qh, const ushort_t* __restrict__ Kh,
    const ushort_t* __restrict__ Vh, const float* __restrict__ emb,
    const int* __restrict__ offsets, const int* __restrict__ colIdx,
    const float* __restrict__ gam, const float* __restrict__ bet,
    float* __restrict__ out)
{
    const int node = (int)((blockIdx.x * blockDim.x + threadIdx.x) >> 6);
    if (node >= N_NODES) return;
    const int lane = threadIdx.x & 63;
    const int d0 = lane * 2;

    const float2 q = __half22float2(*(const __half2*)(Qh + (size_t)node * D + d0));
    const float2 r = *(const float2*)(emb + (size_t)node * D + d0);

    const int s = offsets[node];
    const int e = offsets[node + 1];

    float nx = 0.f, ny = 0.f, den = 0.f;
    int i = s;
    for (; i + 4 <= e; i += 4) {
        const int c0 = colIdx[i];
        const int c1 = colIdx[i + 1];
        const int c2 = colIdx[i + 2];
        const int c3 = colIdx[i + 3];
        const float2 k0 = __half22float2(*(const __half2*)(Kh + (size_t)c0 * D + d0));
        const float2 k1 = __half22float2(*(const __half2*)(Kh + (size_t)c1 * D + d0));
        const float2 k2 = __half22float2(*(const __half2*)(Kh + (size_t)c2 * D + d0));
        const float2 k3 = __half22float2(*(const __half2*)(Kh + (size_t)c3 * D + d0));
        const float2 v0 = __half22float2(*(const __half2*)(Vh + (size_t)c0 * D + d0));
        const float2 v1 = __half22float2(*(const __half2*)(Vh + (size_t)c1 * D + d0));
        const float2 v2 = __half22float2(*(const __half2*)(Vh + (size_t)c2 * D + d0));
        const float2 v3 = __half22float2(*(const __half2*)(Vh + (size_t)c3 * D + d0));
        float p0 = hsum(q.x * k0.x + q.y * k0.y);
        float p1 = hsum(q.x * k1.x + q.y * k1.y);
        float p2 = hsum(q.x * k2.x + q.y * k2.y);
        float p3 = hsum(q.x * k3.x + q.y * k3.y);
        const float w0 = __expf(fminf(10.f, fmaxf(-10.f, p0)));
        const float w1 = __expf(fminf(10.f, fmaxf(-10.f, p1)));
        const float w2 = __expf(fminf(10.f, fmaxf(-10.f, p2)));
        const float w3 = __expf(fminf(10.f, fmaxf(-10.f, p3)));
        den += (w0 + w1) + (w2 + w3);
        nx += w0 * v0.x + w1 * v1.x + w2 * v2.x + w3 * v3.x;
        ny += w0 * v0.y + w1 * v1.y + w2 * v2.y + w3 * v3.y;
    }
    for (; i < e; ++i) {
        const int c0 = colIdx[i];
        const float2 k0 = __half22float2(*(const __half2*)(Kh + (size_t)c0 * D + d0));
        const float2 v0 = __half22float2(*(const __half2*)(Vh + (size_t)c0 * D + d0));
        float p0 = hsum(q.x * k0.x + q.y * k0.y);
        const float w0 = __expf(fminf(10.f, fmaxf(-10.f, p0)));
        den += w0;
        nx += w0 * v0.x;
        ny += w0 * v0.y;
    }

    const float inv = 1.f / (den + 1e-8f);
    const float rx = nx * inv + r.x;
    const float ry = ny * inv + r.y;

    float sum = rx + ry;
    float ssq = rx * rx + ry * ry;
    #pragma unroll
    for (int o = 1; o < 64; o <<= 1) {
        sum += __shfl_xor(sum, o);
        ssq += __shfl_xor(ssq, o);
    }
    const float mu   = sum * (1.f / 128.f);
    const float var  = ssq * (1.f / 128.f) - mu * mu;
    const float rstd = rsqrtf(var + 1e-6f);

    const float2 g = *(const float2*)(gam + d0);
    const float2 b = *(const float2*)(bet + d0);
    float2 o2;
    o2.x = (rx - mu) * rstd * g.x + b.x;
    o2.y = (ry - mu) * rstd * g.y + b.y;
    *(float2*)(out + (size_t)node * D + d0) = o2;
}

// ---------------------------------------------------------------------------
extern "C" void kernel_launch(void* const* d_in, const int* in_sizes, int n_in,
                              void* d_out, int out_size, void* d_ws, size_t ws_size,
                              hipStream_t stream)
{
    const float* emb  = (const float*)d_in[0];
    const int*   ei   = (const int*)d_in[1];
    const float* Wq   = (const float*)d_in[2];
    const float* Wk   = (const float*)d_in[3];
    const float* Wv   = (const float*)d_in[4];
    const float* gam  = (const float*)d_in[5];
    const float* bet  = (const float*)d_in[6];
    float*       out  = (float*)d_out;

    const int* rows = ei;
    const int* cols = ei + N_EDGES;

    char* ws = (char*)d_ws;
    auto alloc = [&](size_t bytes) {
        char* p = ws;
        ws += (bytes + 255) & ~size_t(255);
        return p;
    };
    ushort_t* Qh      = (ushort_t*)alloc((size_t)N_NODES * D * sizeof(ushort_t));
    ushort_t* Kh      = (ushort_t*)alloc((size_t)N_NODES * D * sizeof(ushort_t));
    ushort_t* Vh      = (ushort_t*)alloc((size_t)N_NODES * D * sizeof(ushort_t));
    ushort_t* embH    = (ushort_t*)alloc((size_t)N_NODES * D * sizeof(ushort_t));
    ushort_t* WpAll   = (ushort_t*)alloc((size_t)3 * D * D * sizeof(ushort_t));
    int*      counts  = (int*)alloc((size_t)N_NODES * sizeof(int));
    int*      offsets = (int*)alloc((size_t)(N_NODES + 1) * sizeof(int));
    int*      cursor  = (int*)alloc((size_t)N_NODES * sizeof(int));
    int*      colIdx  = (int*)alloc((size_t)N_EDGES * sizeof(int));

    hipMemsetAsync(counts, 0, (size_t)N_NODES * sizeof(int), stream);

    conv_emb<<<(N_NODES * D / 8 + 255) / 256, 256, 0, stream>>>(emb, embH);
    repack_w<<<3, 256, 0, stream>>>(Wq, Wk, Wv, WpAll);
    qkv_mfma<<<dim3((N_NODES + 63) / 64, 3), 256, 0, stream>>>(embH, WpAll, Qh, Kh, Vh);

    const int eb = (N_EDGES + 255) / 256;
    count_edges<<<eb, 256, 0, stream>>>(rows, counts);
    scan_offsets<<<1, 1024, 0, stream>>>(counts, offsets, cursor);
    fill_csr<<<eb, 256, 0, stream>>>(rows, cols, cursor, colIdx);

    node_attn<<<(N_NODES * 64 + 255) / 256, 256, 0, stream>>>(
        Qh, Kh, Vh, emb, offsets, colIdx, gam, bet, out);
}

// Round 4
// 268.140 us; speedup vs baseline: 1.8679x; 1.3683x over previous
//
#include <hip/hip_runtime.h>
#include <hip/hip_fp16.h>
#include <cstdint>

#define N_NODES 50000
#define N_EDGES 800000
#define D 128
#define SCAN_B 1024
#define SCAN_NBLK ((N_NODES + SCAN_B - 1) / SCAN_B)   // 49

typedef _Float16 half8 __attribute__((ext_vector_type(8)));
typedef __attribute__((ext_vector_type(4))) float float4v;
typedef unsigned short ushort_t;

__device__ __forceinline__ ushort_t f2h(float f) {
    return __half_as_ushort(__float2half(f));   // RNE hardware cvt
}

// ---------------------------------------------------------------------------
// Convert emb (fp32) -> fp16 row-major. 8 floats per thread.
// ---------------------------------------------------------------------------
__global__ __launch_bounds__(256) void conv_emb(const float* __restrict__ emb,
                                                ushort_t* __restrict__ embH)
{
    const int i = (blockIdx.x * blockDim.x + threadIdx.x) * 8;
    if (i >= N_NODES * D) return;
    const float4 f0 = *(const float4*)(emb + i);
    const float4 f1 = *(const float4*)(emb + i + 4);
    ushort_t r[8];
    r[0]=f2h(f0.x); r[1]=f2h(f0.y); r[2]=f2h(f0.z); r[3]=f2h(f0.w);
    r[4]=f2h(f1.x); r[5]=f2h(f1.y); r[6]=f2h(f1.z); r[7]=f2h(f1.w);
    *(int4*)(embH + i) = *(int4*)r;
}

// ---------------------------------------------------------------------------
// Repack W [K=128][N=128] row-major fp32 -> fp16 in MFMA B-fragment order.
// ---------------------------------------------------------------------------
__global__ __launch_bounds__(256) void repack_w(
    const float* __restrict__ Wq, const float* __restrict__ Wk,
    const float* __restrict__ Wv, ushort_t* __restrict__ WpAll)
{
    const float* W = (blockIdx.x == 0) ? Wq : (blockIdx.x == 1) ? Wk : Wv;
    ushort_t* Wp = WpAll + blockIdx.x * (D * D);
    for (int i = threadIdx.x; i < D * D; i += 256) {
        const int j    = i & 7;
        const int lane = (i >> 3) & 63;
        const int f    = i >> 9;
        const int kk = f >> 3, nt = f & 7;
        const int k = kk * 32 + (lane >> 4) * 8 + j;
        const int n = nt * 16 + (lane & 15);
        Wp[i] = f2h(W[k * D + n]);
    }
}

// ---------------------------------------------------------------------------
// QKV GEMM via MFMA 16x16x32 f16 (fp32 accumulate), outputs stored fp16.
// ---------------------------------------------------------------------------
__global__ __launch_bounds__(256) void qkv_mfma(
    const ushort_t* __restrict__ embH, const ushort_t* __restrict__ WpAll,
    ushort_t* __restrict__ Qh, ushort_t* __restrict__ Kh, ushort_t* __restrict__ Vh)
{
    __shared__ ushort_t sB[D * D];   // 32 KB

    const ushort_t* Wp = WpAll + blockIdx.y * (D * D);
    ushort_t* O = (blockIdx.y == 0) ? Qh : (blockIdx.y == 1) ? Kh : Vh;

    const int t = threadIdx.x;
    for (int i = t * 8; i < D * D; i += 256 * 8)
        *(int4*)(sB + i) = *(const int4*)(Wp + i);
    __syncthreads();

    const int wave = t >> 6;
    const int lane = t & 63;
    const int row0 = blockIdx.x * 64 + wave * 16;
    const int m    = lane & 15;
    const int q    = lane >> 4;

    const int arow = min(row0 + m, N_NODES - 1);
    const ushort_t* abase = embH + (size_t)arow * D + q * 8;
    half8 a[4];
    #pragma unroll
    for (int kk = 0; kk < 4; ++kk)
        a[kk] = *(const half8*)(abase + kk * 32);

    float4v acc[8];
    #pragma unroll
    for (int nt = 0; nt < 8; ++nt) acc[nt] = (float4v){0.f, 0.f, 0.f, 0.f};

    #pragma unroll
    for (int kk = 0; kk < 4; ++kk) {
        #pragma unroll
        for (int nt = 0; nt < 8; ++nt) {
            const half8 b = *(const half8*)(sB + ((kk * 8 + nt) * 64 + lane) * 8);
            acc[nt] = __builtin_amdgcn_mfma_f32_16x16x32_f16(a[kk], b, acc[nt], 0, 0, 0);
        }
    }

    #pragma unroll
    for (int nt = 0; nt < 8; ++nt) {
        #pragma unroll
        for (int r = 0; r < 4; ++r) {
            const int row = row0 + q * 4 + r;
            if (row < N_NODES)
                O[(size_t)row * D + nt * 16 + m] = f2h(acc[nt][r]);
        }
    }
}

// ---------------------------------------------------------------------------
// CSR build: count -> hierarchical scan (3 parallel kernels) -> fill
// ---------------------------------------------------------------------------
__global__ void count_edges(const int* __restrict__ rows, int* __restrict__ counts)
{
    int e = blockIdx.x * blockDim.x + threadIdx.x;
    if (e < N_EDGES) atomicAdd(&counts[rows[e]], 1);
}

__global__ __launch_bounds__(SCAN_B) void scan_blocksums(
    const int* __restrict__ counts, int* __restrict__ blockSums)
{
    __shared__ int sd[SCAN_B];
    const int t = threadIdx.x;
    const int idx = blockIdx.x * SCAN_B + t;
    sd[t] = (idx < N_NODES) ? counts[idx] : 0;
    __syncthreads();
    #pragma unroll
    for (int off = SCAN_B / 2; off > 0; off >>= 1) {
        if (t < off) sd[t] += sd[t + off];
        __syncthreads();
    }
    if (t == 0) blockSums[blockIdx.x] = sd[0];
}

__global__ __launch_bounds__(64) void scan_blockprefix(
    const int* __restrict__ blockSums, int* __restrict__ blockPrefix)
{
    const int lane = threadIdx.x;
    int x = (lane < SCAN_NBLK) ? blockSums[lane] : 0;
    int val = x;
    #pragma unroll
    for (int off = 1; off < 64; off <<= 1) {
        const int y = __shfl_up(val, off);
        if (lane >= off) val += y;
    }
    if (lane < SCAN_NBLK) blockPrefix[lane] = val - x;   // exclusive
}

__global__ __launch_bounds__(SCAN_B) void scan_writeback(
    const int* __restrict__ counts, const int* __restrict__ blockPrefix,
    int* __restrict__ offsets, int* __restrict__ cursor)
{
    __shared__ int sd[SCAN_B];
    const int t = threadIdx.x;
    const int idx = blockIdx.x * SCAN_B + t;
    const int x = (idx < N_NODES) ? counts[idx] : 0;
    int val = x;
    sd[t] = val;
    __syncthreads();
    #pragma unroll
    for (int off = 1; off < SCAN_B; off <<= 1) {
        const int y = (t >= off) ? sd[t - off] : 0;
        __syncthreads();
        val += y;
        sd[t] = val;
        __syncthreads();
    }
    if (idx < N_NODES) {
        const int excl = blockPrefix[blockIdx.x] + val - x;
        offsets[idx] = excl;
        cursor[idx]  = excl;
    }
    if (idx == N_NODES - 1) offsets[N_NODES] = N_EDGES;
}

__global__ void fill_csr(const int* __restrict__ rows, const int* __restrict__ cols,
                         int* __restrict__ cursor, int* __restrict__ colIdx)
{
    int e = blockIdx.x * blockDim.x + threadIdx.x;
    if (e < N_EDGES) {
        const int pos = atomicAdd(&cursor[rows[e]], 1);
        colIdx[pos] = cols[e];
    }
}

// ---------------------------------------------------------------------------
// Node attention: one 64-lane wave per destination node; fp16 Q/K/V gather.
// ---------------------------------------------------------------------------
__device__ __forceinline__ float hsum(float p) {
    p += __shfl_xor(p, 1); p += __shfl_xor(p, 2); p += __shfl_xor(p, 4);
    return p;
}

__global__ __launch_bounds__(256) void node_attn(
    const ushort_t* __restrict__ Qh, const ushort_t* __restrict__ Kh,
    const ushort_t* __restrict__ Vh, const float* __restrict__ emb,
    const int* __restrict__ offsets, const int* __restrict__ colIdx,
    const float* __restrict__ gam, const float* __restrict__ bet,
    float* __restrict__ out)
{
    const int node = (int)((blockIdx.x * blockDim.x + threadIdx.x) >> 6);
    if (node >= N_NODES) return;
    const int lane = threadIdx.x & 63;
    const int d0 = lane * 2;

    const float2 q = __half22float2(*(const __half2*)(Qh + (size_t)node * D + d0));
    const float2 r = *(const float2*)(emb + (size_t)node * D + d0);

    const int s = offsets[node];
    const int e = offsets[node + 1];

    float nx = 0.f, ny = 0.f, den = 0.f;
    int i = s;
    for (; i + 4 <= e; i += 4) {
        const int c0 = colIdx[i];
        const int c1 = colIdx[i + 1];
        const int c2 = colIdx[i + 2];
        const int c3 = colIdx[i + 3];
        const float2 k0 = __half22float2(*(const __half2*)(Kh + (size_t)c0 * D + d0));
        const float2 k1 = __half22float2(*(const __half2*)(Kh + (size_t)c1 * D + d0));
        const float2 k2 = __half22float2(*(const __half2*)(Kh + (size_t)c2 * D + d0));
        const float2 k3 = __half22float2(*(const __half2*)(Kh + (size_t)c3 * D + d0));
        const float2 v0 = __half22float2(*(const __half2*)(Vh + (size_t)c0 * D + d0));
        const float2 v1 = __half22float2(*(const __half2*)(Vh + (size_t)c1 * D + d0));
        const float2 v2 = __half22float2(*(const __half2*)(Vh + (size_t)c2 * D + d0));
        const float2 v3 = __half22float2(*(const __half2*)(Vh + (size_t)c3 * D + d0));
        float p0 = hsum(q.x * k0.x + q.y * k0.y);
        float p1 = hsum(q.x * k1.x + q.y * k1.y);
        float p2 = hsum(q.x * k2.x + q.y * k2.y);
        float p3 = hsum(q.x * k3.x + q.y * k3.y);
        const float w0 = __expf(fminf(10.f, fmaxf(-10.f, p0)));
        const float w1 = __expf(fminf(10.f, fmaxf(-10.f, p1)));
        const float w2 = __expf(fminf(10.f, fmaxf(-10.f, p2)));
        const float w3 = __expf(fminf(10.f, fmaxf(-10.f, p3)));
        den += (w0 + w1) + (w2 + w3);
        nx += w0 * v0.x + w1 * v1.x + w2 * v2.x + w3 * v3.x;
        ny += w0 * v0.y + w1 * v1.y + w2 * v2.y + w3 * v3.y;
    }
    for (; i < e; ++i) {
        const int c0 = colIdx[i];
        const float2 k0 = __half22float2(*(const __half2*)(Kh + (size_t)c0 * D + d0));
        const float2 v0 = __half22float2(*(const __half2*)(Vh + (size_t)c0 * D + d0));
        float p0 = hsum(q.x * k0.x + q.y * k0.y);
        const float w0 = __expf(fminf(10.f, fmaxf(-10.f, p0)));
        den += w0;
        nx += w0 * v0.x;
        ny += w0 * v0.y;
    }

    const float inv = 1.f / (den + 1e-8f);
    const float rx = nx * inv + r.x;
    const float ry = ny * inv + r.y;

    float sum = rx + ry;
    float ssq = rx * rx + ry * ry;
    #pragma unroll
    for (int o = 1; o < 64; o <<= 1) {
        sum += __shfl_xor(sum, o);
        ssq += __shfl_xor(ssq, o);
    }
    const float mu   = sum * (1.f / 128.f);
    const float var  = ssq * (1.f / 128.f) - mu * mu;
    const float rstd = rsqrtf(var + 1e-6f);

    const float2 g = *(const float2*)(gam + d0);
    const float2 b = *(const float2*)(bet + d0);
    float2 o2;
    o2.x = (rx - mu) * rstd * g.x + b.x;
    o2.y = (ry - mu) * rstd * g.y + b.y;
    *(float2*)(out + (size_t)node * D + d0) = o2;
}

// ---------------------------------------------------------------------------
extern "C" void kernel_launch(void* const* d_in, const int* in_sizes, int n_in,
                              void* d_out, int out_size, void* d_ws, size_t ws_size,
                              hipStream_t stream)
{
    const float* emb  = (const float*)d_in[0];
    const int*   ei   = (const int*)d_in[1];
    const float* Wq   = (const float*)d_in[2];
    const float* Wk   = (const float*)d_in[3];
    const float* Wv   = (const float*)d_in[4];
    const float* gam  = (const float*)d_in[5];
    const float* bet  = (const float*)d_in[6];
    float*       out  = (float*)d_out;

    const int* rows = ei;
    const int* cols = ei + N_EDGES;

    char* ws = (char*)d_ws;
    auto alloc = [&](size_t bytes) {
        char* p = ws;
        ws += (bytes + 255) & ~size_t(255);
        return p;
    };
    ushort_t* Qh      = (ushort_t*)alloc((size_t)N_NODES * D * sizeof(ushort_t));
    ushort_t* Kh      = (ushort_t*)alloc((size_t)N_NODES * D * sizeof(ushort_t));
    ushort_t* Vh      = (ushort_t*)alloc((size_t)N_NODES * D * sizeof(ushort_t));
    ushort_t* embH    = (ushort_t*)alloc((size_t)N_NODES * D * sizeof(ushort_t));
    ushort_t* WpAll   = (ushort_t*)alloc((size_t)3 * D * D * sizeof(ushort_t));
    int*      counts  = (int*)alloc((size_t)N_NODES * sizeof(int));
    int*      offsets = (int*)alloc((size_t)(N_NODES + 1) * sizeof(int));
    int*      cursor  = (int*)alloc((size_t)N_NODES * sizeof(int));
    int*      colIdx  = (int*)alloc((size_t)N_EDGES * sizeof(int));
    int*      blockSums   = (int*)alloc((size_t)SCAN_NBLK * sizeof(int));
    int*      blockPrefix = (int*)alloc((size_t)SCAN_NBLK * sizeof(int));

    hipMemsetAsync(counts, 0, (size_t)N_NODES * sizeof(int), stream);

    conv_emb<<<(N_NODES * D / 8 + 255) / 256, 256, 0, stream>>>(emb, embH);
    repack_w<<<3, 256, 0, stream>>>(Wq, Wk, Wv, WpAll);
    qkv_mfma<<<dim3((N_NODES + 63) / 64, 3), 256, 0, stream>>>(embH, WpAll, Qh, Kh, Vh);

    const int eb = (N_EDGES + 255) / 256;
    count_edges<<<eb, 256, 0, stream>>>(rows, counts);
    scan_blocksums<<<SCAN_NBLK, SCAN_B, 0, stream>>>(counts, blockSums);
    scan_blockprefix<<<1, 64, 0, stream>>>(blockSums, blockPrefix);
    scan_writeback<<<SCAN_NBLK, SCAN_B, 0, stream>>>(counts, blockPrefix, offsets, cursor);
    fill_csr<<<eb, 256, 0, stream>>>(rows, cols, cursor, colIdx);

    node_attn<<<(N_NODES * 64 + 255) / 256, 256, 0, stream>>>(
        Qh, Kh, Vh, emb, offsets, colIdx, gam, bet, out);
}

// Round 5
// 262.307 us; speedup vs baseline: 1.9095x; 1.0222x over previous
//
#include <hip/hip_runtime.h>
#include <hip/hip_fp16.h>
#include <cstdint>

#define N_NODES 50000
#define N_EDGES 800000
#define D 128
#define SCAN_B 1024
#define SCAN_NBLK ((N_NODES + SCAN_B - 1) / SCAN_B)   // 49

typedef _Float16 half8 __attribute__((ext_vector_type(8)));
typedef _Float16 half2_t __attribute__((ext_vector_type(2)));
typedef __attribute__((ext_vector_type(4))) float float4v;
typedef unsigned short ushort_t;

__device__ __forceinline__ ushort_t f2h(float f) {
    return __half_as_ushort(__float2half(f));   // RNE hardware cvt
}
__device__ __forceinline__ half2_t u2h2(unsigned u) {
    union { unsigned u; half2_t h; } c; c.u = u; return c.h;
}

// ---------------------------------------------------------------------------
// prep: blocks 0..2 repack W fp32 -> fp16 B-fragment order;
//       blocks 3..  count edges (4 edges/thread, int4 loads).
// ---------------------------------------------------------------------------
__global__ __launch_bounds__(256) void prep(
    const float* __restrict__ Wq, const float* __restrict__ Wk,
    const float* __restrict__ Wv, ushort_t* __restrict__ WpAll,
    const int* __restrict__ rows, int* __restrict__ counts)
{
    if (blockIdx.x < 3) {
        const float* W = (blockIdx.x == 0) ? Wq : (blockIdx.x == 1) ? Wk : Wv;
        ushort_t* Wp = WpAll + blockIdx.x * (D * D);
        for (int i = threadIdx.x; i < D * D; i += 256) {
            const int j    = i & 7;
            const int lane = (i >> 3) & 63;
            const int f    = i >> 9;
            const int kk = f >> 3, nt = f & 7;
            const int k = kk * 32 + (lane >> 4) * 8 + j;
            const int n = nt * 16 + (lane & 15);
            Wp[i] = f2h(W[k * D + n]);
        }
    } else {
        const int e0 = ((blockIdx.x - 3) * 256 + threadIdx.x) * 4;
        if (e0 + 4 <= N_EDGES) {
            const int4 r = *(const int4*)(rows + e0);
            atomicAdd(&counts[r.x], 1);
            atomicAdd(&counts[r.y], 1);
            atomicAdd(&counts[r.z], 1);
            atomicAdd(&counts[r.w], 1);
        } else {
            for (int e = e0; e < N_EDGES; ++e) atomicAdd(&counts[rows[e]], 1);
        }
    }
}

// ---------------------------------------------------------------------------
// QKV GEMM via MFMA 16x16x32 f16, fp32 emb input (converted in-register).
// Outputs: Qh [node][128] fp16; KVh [node][256] fp16 (K | V interleaved).
// ---------------------------------------------------------------------------
__global__ __launch_bounds__(256) void qkv_mfma(
    const float* __restrict__ emb, const ushort_t* __restrict__ WpAll,
    ushort_t* __restrict__ Qh, ushort_t* __restrict__ KVh)
{
    __shared__ ushort_t sB[D * D];   // 32 KB

    const ushort_t* Wp = WpAll + blockIdx.y * (D * D);

    const int t = threadIdx.x;
    for (int i = t * 8; i < D * D; i += 256 * 8)
        *(int4*)(sB + i) = *(const int4*)(Wp + i);
    __syncthreads();

    const int wave = t >> 6;
    const int lane = t & 63;
    const int row0 = blockIdx.x * 64 + wave * 16;
    const int m    = lane & 15;
    const int q    = lane >> 4;

    const int arow = min(row0 + m, N_NODES - 1);
    const float* abase = emb + (size_t)arow * D + q * 8;
    half8 a[4];
    #pragma unroll
    for (int kk = 0; kk < 4; ++kk) {
        const float4 f0 = *(const float4*)(abase + kk * 32);
        const float4 f1 = *(const float4*)(abase + kk * 32 + 4);
        a[kk][0] = (_Float16)f0.x; a[kk][1] = (_Float16)f0.y;
        a[kk][2] = (_Float16)f0.z; a[kk][3] = (_Float16)f0.w;
        a[kk][4] = (_Float16)f1.x; a[kk][5] = (_Float16)f1.y;
        a[kk][6] = (_Float16)f1.z; a[kk][7] = (_Float16)f1.w;
    }

    float4v acc[8];
    #pragma unroll
    for (int nt = 0; nt < 8; ++nt) acc[nt] = (float4v){0.f, 0.f, 0.f, 0.f};

    #pragma unroll
    for (int kk = 0; kk < 4; ++kk) {
        #pragma unroll
        for (int nt = 0; nt < 8; ++nt) {
            const half8 b = *(const half8*)(sB + ((kk * 8 + nt) * 64 + lane) * 8);
            acc[nt] = __builtin_amdgcn_mfma_f32_16x16x32_f16(a[kk], b, acc[nt], 0, 0, 0);
        }
    }

    ushort_t* O;
    int rs, off;
    if (blockIdx.y == 0) { O = Qh;  rs = 128; off = 0; }
    else if (blockIdx.y == 1) { O = KVh; rs = 256; off = 0; }
    else { O = KVh; rs = 256; off = 128; }

    #pragma unroll
    for (int nt = 0; nt < 8; ++nt) {
        #pragma unroll
        for (int r = 0; r < 4; ++r) {
            const int row = row0 + q * 4 + r;
            if (row < N_NODES)
                O[(size_t)row * rs + off + nt * 16 + m] = f2h(acc[nt][r]);
        }
    }
}

// ---------------------------------------------------------------------------
// Hierarchical scan (2 kernels; writeback recomputes block prefix inline)
// ---------------------------------------------------------------------------
__global__ __launch_bounds__(SCAN_B) void scan_blocksums(
    const int* __restrict__ counts, int* __restrict__ blockSums)
{
    __shared__ int sd[SCAN_B];
    const int t = threadIdx.x;
    const int idx = blockIdx.x * SCAN_B + t;
    sd[t] = (idx < N_NODES) ? counts[idx] : 0;
    __syncthreads();
    #pragma unroll
    for (int off = SCAN_B / 2; off > 0; off >>= 1) {
        if (t < off) sd[t] += sd[t + off];
        __syncthreads();
    }
    if (t == 0) blockSums[blockIdx.x] = sd[0];
}

__global__ __launch_bounds__(SCAN_B) void scan_writeback(
    const int* __restrict__ counts, const int* __restrict__ blockSums,
    int* __restrict__ offsets, int* __restrict__ cursor)
{
    __shared__ int sd[SCAN_B];
    __shared__ int sPre[64];
    const int t = threadIdx.x;

    if (t < 64) {
        const int lane = t;
        int x = (lane < SCAN_NBLK) ? blockSums[lane] : 0;
        int val = x;
        #pragma unroll
        for (int off = 1; off < 64; off <<= 1) {
            const int y = __shfl_up(val, off);
            if (lane >= off) val += y;
        }
        sPre[lane] = val - x;   // exclusive
    }

    const int idx = blockIdx.x * SCAN_B + t;
    const int x = (idx < N_NODES) ? counts[idx] : 0;
    int val = x;
    sd[t] = val;
    __syncthreads();
    #pragma unroll
    for (int off = 1; off < SCAN_B; off <<= 1) {
        const int y = (t >= off) ? sd[t - off] : 0;
        __syncthreads();
        val += y;
        sd[t] = val;
        __syncthreads();
    }
    if (idx < N_NODES) {
        const int excl = sPre[blockIdx.x] + val - x;
        offsets[idx] = excl;
        cursor[idx]  = excl;
    }
    if (idx == N_NODES - 1) offsets[N_NODES] = N_EDGES;
}

__global__ void fill_csr(const int* __restrict__ rows, const int* __restrict__ cols,
                         int* __restrict__ cursor, int* __restrict__ colIdx)
{
    int e = blockIdx.x * blockDim.x + threadIdx.x;
    if (e < N_EDGES) {
        const int pos = atomicAdd(&cursor[rows[e]], 1);
        colIdx[pos] = cols[e];
    }
}

// ---------------------------------------------------------------------------
// Node attention v2: one 64-lane wave per node, split into two 32-lane
// halves; each half processes a different edge. Lane owns 4 dims
// (d0 = (lane&31)*4); head = 4 lanes -> 2-step hsum. fp16 dot2 for QK.
// ---------------------------------------------------------------------------
__global__ __launch_bounds__(256) void node_attn(
    const ushort_t* __restrict__ Qh, const ushort_t* __restrict__ KVh,
    const float* __restrict__ emb,
    const int* __restrict__ offsets, const int* __restrict__ colIdx,
    const float* __restrict__ gam, const float* __restrict__ bet,
    float* __restrict__ out)
{
    const int node = (int)((blockIdx.x * blockDim.x + threadIdx.x) >> 6);
    if (node >= N_NODES) return;
    const int lane = threadIdx.x & 63;
    const int half = lane >> 5;
    const int l5   = lane & 31;
    const int d0   = l5 * 4;

    const uint2 qw = *(const uint2*)(Qh + (size_t)node * D + d0);
    const half2_t q01 = u2h2(qw.x);
    const half2_t q23 = u2h2(qw.y);
    const float4 r4 = *(const float4*)(emb + (size_t)node * D + d0);

    const int s = offsets[node];
    const int e = offsets[node + 1];

    float a0 = 0.f, a1 = 0.f, a2 = 0.f, a3 = 0.f, den = 0.f;

    int i = s;
    // main loop: 4 valid edges per iteration (2 per half)
    for (; i + 4 <= e; i += 4) {
        const int cA = colIdx[i + half];
        const int cB = colIdx[i + 2 + half];
        const ushort_t* rowA = KVh + (size_t)cA * 256 + d0;
        const ushort_t* rowB = KVh + (size_t)cB * 256 + d0;
        const uint2 kA = *(const uint2*)(rowA);
        const uint2 vA = *(const uint2*)(rowA + 128);
        const uint2 kB = *(const uint2*)(rowB);
        const uint2 vB = *(const uint2*)(rowB + 128);

        float pA = __builtin_amdgcn_fdot2(q01, u2h2(kA.x), 0.f, false);
        pA = __builtin_amdgcn_fdot2(q23, u2h2(kA.y), pA, false);
        float pB = __builtin_amdgcn_fdot2(q01, u2h2(kB.x), 0.f, false);
        pB = __builtin_amdgcn_fdot2(q23, u2h2(kB.y), pB, false);
        pA += __shfl_xor(pA, 1); pA += __shfl_xor(pA, 2);
        pB += __shfl_xor(pB, 1); pB += __shfl_xor(pB, 2);
        const float wA = __expf(fminf(10.f, fmaxf(-10.f, pA)));
        const float wB = __expf(fminf(10.f, fmaxf(-10.f, pB)));
        den += wA + wB;

        const half2_t vA01 = u2h2(vA.x), vA23 = u2h2(vA.y);
        const half2_t vB01 = u2h2(vB.x), vB23 = u2h2(vB.y);
        a0 += wA * (float)vA01[0] + wB * (float)vB01[0];
        a1 += wA * (float)vA01[1] + wB * (float)vB01[1];
        a2 += wA * (float)vA23[0] + wB * (float)vB23[0];
        a3 += wA * (float)vA23[1] + wB * (float)vB23[1];
    }
    // tail: up to 3 edges, masked (2 per trip)
    for (; i < e; i += 2) {
        const int idx = i + half;
        const int c = colIdx[(idx < e) ? idx : (e - 1)];
        const ushort_t* row = KVh + (size_t)c * 256 + d0;
        const uint2 kk = *(const uint2*)(row);
        const uint2 vv = *(const uint2*)(row + 128);
        float p = __builtin_amdgcn_fdot2(q01, u2h2(kk.x), 0.f, false);
        p = __builtin_amdgcn_fdot2(q23, u2h2(kk.y), p, false);
        p += __shfl_xor(p, 1); p += __shfl_xor(p, 2);
        float w = __expf(fminf(10.f, fmaxf(-10.f, p)));
        w = (idx < e) ? w : 0.f;
        den += w;
        const half2_t v01 = u2h2(vv.x), v23 = u2h2(vv.y);
        a0 += w * (float)v01[0];
        a1 += w * (float)v01[1];
        a2 += w * (float)v23[0];
        a3 += w * (float)v23[1];
    }

    // fold halves: both halves end up with full sums
    a0 += __shfl_xor(a0, 32);
    a1 += __shfl_xor(a1, 32);
    a2 += __shfl_xor(a2, 32);
    a3 += __shfl_xor(a3, 32);
    den += __shfl_xor(den, 32);

    const float inv = 1.f / (den + 1e-8f);
    const float r0 = a0 * inv + r4.x;
    const float r1 = a1 * inv + r4.y;
    const float r2 = a2 * inv + r4.z;
    const float r3 = a3 * inv + r4.w;

    // LayerNorm: each dim appears twice across the wave -> divide by 256
    float sum = (r0 + r1) + (r2 + r3);
    float ssq = (r0 * r0 + r1 * r1) + (r2 * r2 + r3 * r3);
    #pragma unroll
    for (int o = 1; o < 64; o <<= 1) {
        sum += __shfl_xor(sum, o);
        ssq += __shfl_xor(ssq, o);
    }
    const float mu   = sum * (1.f / 256.f);
    const float var  = ssq * (1.f / 256.f) - mu * mu;
    const float rstd = rsqrtf(var + 1e-6f);

    if (half == 0) {
        const float4 g = *(const float4*)(gam + d0);
        const float4 b = *(const float4*)(bet + d0);
        float4 o4;
        o4.x = (r0 - mu) * rstd * g.x + b.x;
        o4.y = (r1 - mu) * rstd * g.y + b.y;
        o4.z = (r2 - mu) * rstd * g.z + b.z;
        o4.w = (r3 - mu) * rstd * g.w + b.w;
        *(float4*)(out + (size_t)node * D + d0) = o4;
    }
}

// ---------------------------------------------------------------------------
extern "C" void kernel_launch(void* const* d_in, const int* in_sizes, int n_in,
                              void* d_out, int out_size, void* d_ws, size_t ws_size,
                              hipStream_t stream)
{
    const float* emb  = (const float*)d_in[0];
    const int*   ei   = (const int*)d_in[1];
    const float* Wq   = (const float*)d_in[2];
    const float* Wk   = (const float*)d_in[3];
    const float* Wv   = (const float*)d_in[4];
    const float* gam  = (const float*)d_in[5];
    const float* bet  = (const float*)d_in[6];
    float*       out  = (float*)d_out;

    const int* rows = ei;
    const int* cols = ei + N_EDGES;

    char* ws = (char*)d_ws;
    auto alloc = [&](size_t bytes) {
        char* p = ws;
        ws += (bytes + 255) & ~size_t(255);
        return p;
    };
    ushort_t* Qh      = (ushort_t*)alloc((size_t)N_NODES * D * sizeof(ushort_t));
    ushort_t* KVh     = (ushort_t*)alloc((size_t)N_NODES * 2 * D * sizeof(ushort_t));
    ushort_t* WpAll   = (ushort_t*)alloc((size_t)3 * D * D * sizeof(ushort_t));
    int*      counts  = (int*)alloc((size_t)N_NODES * sizeof(int));
    int*      offsets = (int*)alloc((size_t)(N_NODES + 1) * sizeof(int));
    int*      cursor  = (int*)alloc((size_t)N_NODES * sizeof(int));
    int*      colIdx  = (int*)alloc((size_t)N_EDGES * sizeof(int));
    int*      blockSums = (int*)alloc((size_t)SCAN_NBLK * sizeof(int));

    hipMemsetAsync(counts, 0, (size_t)N_NODES * sizeof(int), stream);

    const int cntBlocks = (N_EDGES + 1023) / 1024;   // 4 edges/thread
    prep<<<3 + cntBlocks, 256, 0, stream>>>(Wq, Wk, Wv, WpAll, rows, counts);

    qkv_mfma<<<dim3((N_NODES + 63) / 64, 3), 256, 0, stream>>>(emb, WpAll, Qh, KVh);

    scan_blocksums<<<SCAN_NBLK, SCAN_B, 0, stream>>>(counts, blockSums);
    scan_writeback<<<SCAN_NBLK, SCAN_B, 0, stream>>>(counts, blockSums, offsets, cursor);

    fill_csr<<<(N_EDGES + 255) / 256, 256, 0, stream>>>(rows, cols, cursor, colIdx);

    node_attn<<<(N_NODES * 64 + 255) / 256, 256, 0, stream>>>(
        Qh, KVh, emb, offsets, colIdx, gam, bet, out);
}